// Round 1
// baseline (354.616 us; speedup 1.0000x reference)
//
#include <hip/hip_runtime.h>

#define B_ 2
#define V_ 8
#define C_ 32
#define H_ 256
#define W_ 320
#define HW_ (H_ * W_)

__global__ __launch_bounds__(256) void feature_projector_kernel(
    const float* __restrict__ features,     // (B,V,C,H,W)
    const float* __restrict__ projections,  // (B,V,4,4)
    const float* __restrict__ depth,        // (B, H*W)
    float* __restrict__ out)                // (B,V,C,H,W)
{
    const int n = blockIdx.y;                 // view index 0..B*V-1 (uniform per block)
    const int b = n / V_;
    const int pix = blockIdx.x * blockDim.x + threadIdx.x;
    if (pix >= HW_) return;

    const int xi = pix % W_;
    const int yi = pix / W_;
    const float xf = (float)xi;
    const float yf = (float)yi;

    // Projection rows (uniform per block -> scalar loads)
    const float* P = projections + n * 16;
    const float r00 = P[0], r01 = P[1], r02 = P[2],  t0 = P[3];
    const float r10 = P[4], r11 = P[5], r12 = P[6],  t1 = P[7];
    const float r20 = P[8], r21 = P[9], r22 = P[10], t2 = P[11];

    const float d = depth[b * HW_ + pix];

    // cg = rot @ [x, y, 1] * d + trans   (match reference op order)
    const float cx = (r00 * xf + r01 * yf + r02) * d + t0;
    const float cy = (r10 * xf + r11 * yf + r12) * d + t1;
    const float cz = (r20 * xf + r21 * yf + r22) * d + t2;

    const float px = cx / cz;
    const float py = cy / cz;
    const float gx = px / (float)(W_ - 1) * 2.0f - 1.0f;
    const float gy = py / (float)(H_ - 1) * 2.0f - 1.0f;

    // grid_sample unnormalize
    const float ix = (gx + 1.0f) * ((float)W_ * 0.5f) - 0.5f;
    const float iy = (gy + 1.0f) * ((float)H_ * 0.5f) - 0.5f;

    const float ix0 = floorf(ix);
    const float iy0 = floorf(iy);
    const float ix1 = ix0 + 1.0f;
    const float iy1 = iy0 + 1.0f;

    const float wx1 = ix - ix0;
    const float wy1 = iy - iy0;
    const float wx0 = 1.0f - wx1;
    const float wy0 = 1.0f - wy1;

    // Validity in float domain (NaN-safe: comparisons with NaN are false)
    const float vx0 = (ix0 >= 0.0f && ix0 <= (float)(W_ - 1)) ? 1.0f : 0.0f;
    const float vx1 = (ix1 >= 0.0f && ix1 <= (float)(W_ - 1)) ? 1.0f : 0.0f;
    const float vy0 = (iy0 >= 0.0f && iy0 <= (float)(H_ - 1)) ? 1.0f : 0.0f;
    const float vy1 = (iy1 >= 0.0f && iy1 <= (float)(H_ - 1)) ? 1.0f : 0.0f;

    // Clamp in float BEFORE int conversion (safe for huge/NaN coords)
    const int x0 = (int)fminf(fmaxf(ix0, 0.0f), (float)(W_ - 1));
    const int x1 = (int)fminf(fmaxf(ix1, 0.0f), (float)(W_ - 1));
    const int y0 = (int)fminf(fmaxf(iy0, 0.0f), (float)(H_ - 1));
    const int y1 = (int)fminf(fmaxf(iy1, 0.0f), (float)(H_ - 1));

    // Weights with validity folded in multiplicatively (NaN propagates like ref)
    const float w00 = wx0 * wy0 * (vx0 * vy0);
    const float w01 = wx1 * wy0 * (vx1 * vy0);
    const float w10 = wx0 * wy1 * (vx0 * vy1);
    const float w11 = wx1 * wy1 * (vx1 * vy1);

    const int o00 = y0 * W_ + x0;
    const int o01 = y0 * W_ + x1;
    const int o10 = y1 * W_ + x0;
    const int o11 = y1 * W_ + x1;

    const float* __restrict__ fN = features + (size_t)n * C_ * HW_;
    float* __restrict__ oN = out + (size_t)n * C_ * HW_ + pix;

#pragma unroll 4
    for (int c = 0; c < C_; ++c) {
        const float* __restrict__ fc = fN + (size_t)c * HW_;
        const float v = fc[o00] * w00 + fc[o01] * w01 + fc[o10] * w10 + fc[o11] * w11;
        oN[(size_t)c * HW_] = v;
    }
}

extern "C" void kernel_launch(void* const* d_in, const int* in_sizes, int n_in,
                              void* d_out, int out_size, void* d_ws, size_t ws_size,
                              hipStream_t stream) {
    const float* features    = (const float*)d_in[0];
    const float* projections = (const float*)d_in[1];
    const float* depth       = (const float*)d_in[2];
    float* out = (float*)d_out;

    dim3 block(256, 1, 1);
    dim3 grid(HW_ / 256, B_ * V_, 1);
    feature_projector_kernel<<<grid, block, 0, stream>>>(features, projections, depth, out);
}

// Round 2
// 350.170 us; speedup vs baseline: 1.0127x; 1.0127x over previous
//
#include <hip/hip_runtime.h>

#define B_ 2
#define V_ 8
#define C_ 32
#define H_ 256
#define W_ 320
#define HW_ (H_ * W_)

__global__ __launch_bounds__(256) void feature_projector_kernel(
    const float* __restrict__ features,     // (B,V,C,H,W)
    const float* __restrict__ projections,  // (B,V,4,4)
    const float* __restrict__ depth,        // (B, H*W)
    float* __restrict__ out)                // (B,V,C,H,W)
{
    const int n = blockIdx.y;                 // view index 0..B*V-1 (uniform per block)
    const int b = n >> 3;                     // V_ == 8
    const int pix = blockIdx.x * blockDim.x + threadIdx.x;

    const int xi = pix % W_;
    const int yi = pix / W_;
    const float xf = (float)xi;
    const float yf = (float)yi;

    // Projection rows (uniform per block -> scalar loads)
    const float* P = projections + n * 16;
    const float r00 = P[0], r01 = P[1], r02 = P[2],  t0 = P[3];
    const float r10 = P[4], r11 = P[5], r12 = P[6],  t1 = P[7];
    const float r20 = P[8], r21 = P[9], r22 = P[10], t2 = P[11];

    const float d = depth[b * HW_ + pix];

    // cg = rot @ [x, y, 1] * d + trans   (match reference op order)
    const float cx = (r00 * xf + r01 * yf + r02) * d + t0;
    const float cy = (r10 * xf + r11 * yf + r12) * d + t1;
    const float cz = (r20 * xf + r21 * yf + r22) * d + t2;

    const float px = cx / cz;
    const float py = cy / cz;
    const float gx = px / (float)(W_ - 1) * 2.0f - 1.0f;
    const float gy = py / (float)(H_ - 1) * 2.0f - 1.0f;

    // grid_sample unnormalize
    const float ix = (gx + 1.0f) * ((float)W_ * 0.5f) - 0.5f;
    const float iy = (gy + 1.0f) * ((float)H_ * 0.5f) - 0.5f;

    const float ix0 = floorf(ix);
    const float iy0 = floorf(iy);
    const float ix1 = ix0 + 1.0f;
    const float iy1 = iy0 + 1.0f;

    const float wx1 = ix - ix0;
    const float wy1 = iy - iy0;
    const float wx0 = 1.0f - wx1;
    const float wy0 = 1.0f - wy1;

    const float fW1 = (float)(W_ - 1);
    const float fH1 = (float)(H_ - 1);

    // Validity in float domain (NaN-safe: comparisons with NaN are false)
    const float vx0 = (ix0 >= 0.0f && ix0 <= fW1) ? 1.0f : 0.0f;
    const float vx1 = (ix1 >= 0.0f && ix1 <= fW1) ? 1.0f : 0.0f;
    const float vy0 = (iy0 >= 0.0f && iy0 <= fH1) ? 1.0f : 0.0f;
    const float vy1 = (iy1 >= 0.0f && iy1 <= fH1) ? 1.0f : 0.0f;

    // Clamp in float BEFORE int conversion (safe for huge/NaN coords;
    // fmaxf(NaN,0)=0 so indices are always in-bounds)
    const int xb  = (int)fminf(fmaxf(ix0, 0.0f), (float)(W_ - 2)); // pair base col
    const int x0c = (int)fminf(fmaxf(ix0, 0.0f), fW1);
    const int x1c = (int)fminf(fmaxf(ix1, 0.0f), fW1);
    const int y0c = (int)fminf(fmaxf(iy0, 0.0f), fH1);
    const int y1c = (int)fminf(fmaxf(iy1, 0.0f), fH1);

    // x-weights with validity folded in (NaN propagates like ref)
    const float wxa = wx0 * vx0;
    const float wxb = wx1 * vx1;
    // Redistribute x-weights onto the fetched pair elements [xb, xb+1].
    // Covers: interior (xb=x0c, xb+1=x1c), left clamp (both -> elem0, weights 0),
    // right edge ix0=W-1 (x0c lands on elem1), NaN (xb=x0c=x1c=0, weight NaN).
    const float a0 = (x0c == xb     ? wxa : 0.0f) + (x1c == xb     ? wxb : 0.0f);
    const float a1 = (x0c == xb + 1 ? wxa : 0.0f) + (x1c == xb + 1 ? wxb : 0.0f);
    const float ry0 = wy0 * vy0;
    const float ry1 = wy1 * vy1;

    const int r0 = y0c * W_ + xb;
    const int r1 = y1c * W_ + xb;

    const float* __restrict__ fN = features + (size_t)n * C_ * HW_;
    float* __restrict__ oN = out + (size_t)n * C_ * HW_ + pix;

#pragma unroll 8
    for (int c = 0; c < C_; ++c) {
        const float* __restrict__ fc = fN + (size_t)c * HW_;
        float2 p0, p1;
        __builtin_memcpy(&p0, fc + r0, 8);   // unaligned-capable dwordx2
        __builtin_memcpy(&p1, fc + r1, 8);
        const float v = (p0.x * a0 + p0.y * a1) * ry0
                      + (p1.x * a0 + p1.y * a1) * ry1;
        oN[(size_t)c * HW_] = v;
    }
}

extern "C" void kernel_launch(void* const* d_in, const int* in_sizes, int n_in,
                              void* d_out, int out_size, void* d_ws, size_t ws_size,
                              hipStream_t stream) {
    const float* features    = (const float*)d_in[0];
    const float* projections = (const float*)d_in[1];
    const float* depth       = (const float*)d_in[2];
    float* out = (float*)d_out;

    dim3 block(256, 1, 1);
    dim3 grid(HW_ / 256, B_ * V_, 1);
    feature_projector_kernel<<<grid, block, 0, stream>>>(features, projections, depth, out);
}

// Round 3
// 327.118 us; speedup vs baseline: 1.0841x; 1.0705x over previous
//
#include <hip/hip_runtime.h>

#define B_ 2
#define V_ 8
#define C_ 32
#define H_ 256
#define W_ 320
#define HW_ (H_ * W_)

__global__ __launch_bounds__(256, 4) void feature_projector_kernel(
    const float* __restrict__ features,     // (B,V,C,H,W)
    const float* __restrict__ projections,  // (B,V,4,4)
    const float* __restrict__ depth,        // (B, H*W)
    float* __restrict__ out)                // (B,V,C,H,W)
{
    const int n = blockIdx.y;                 // view index 0..B*V-1 (uniform per block)
    const int b = n >> 3;                     // V_ == 8
    const int pix = blockIdx.x * blockDim.x + threadIdx.x;

    const int xi = pix % W_;
    const int yi = pix / W_;
    const float xf = (float)xi;
    const float yf = (float)yi;

    // Projection rows (uniform per block -> scalar loads)
    const float* P = projections + n * 16;
    const float r00 = P[0], r01 = P[1], r02 = P[2],  t0 = P[3];
    const float r10 = P[4], r11 = P[5], r12 = P[6],  t1 = P[7];
    const float r20 = P[8], r21 = P[9], r22 = P[10], t2 = P[11];

    const float d = depth[b * HW_ + pix];

    // cg = rot @ [x, y, 1] * d + trans   (match reference op order)
    const float cx = (r00 * xf + r01 * yf + r02) * d + t0;
    const float cy = (r10 * xf + r11 * yf + r12) * d + t1;
    const float cz = (r20 * xf + r21 * yf + r22) * d + t2;

    const float px = cx / cz;
    const float py = cy / cz;
    const float gx = px / (float)(W_ - 1) * 2.0f - 1.0f;
    const float gy = py / (float)(H_ - 1) * 2.0f - 1.0f;

    // grid_sample unnormalize
    const float ix = (gx + 1.0f) * ((float)W_ * 0.5f) - 0.5f;
    const float iy = (gy + 1.0f) * ((float)H_ * 0.5f) - 0.5f;

    const float ix0 = floorf(ix);
    const float iy0 = floorf(iy);
    const float ix1 = ix0 + 1.0f;
    const float iy1 = iy0 + 1.0f;

    const float wx1 = ix - ix0;
    const float wy1 = iy - iy0;
    const float wx0 = 1.0f - wx1;
    const float wy0 = 1.0f - wy1;

    const float fW1 = (float)(W_ - 1);
    const float fH1 = (float)(H_ - 1);

    // Validity in float domain (NaN-safe: comparisons with NaN are false)
    const float vx0 = (ix0 >= 0.0f && ix0 <= fW1) ? 1.0f : 0.0f;
    const float vx1 = (ix1 >= 0.0f && ix1 <= fW1) ? 1.0f : 0.0f;
    const float vy0 = (iy0 >= 0.0f && iy0 <= fH1) ? 1.0f : 0.0f;
    const float vy1 = (iy1 >= 0.0f && iy1 <= fH1) ? 1.0f : 0.0f;

    // Clamp in float BEFORE int conversion (safe for huge/NaN coords;
    // fmaxf(NaN,0)=0 so indices are always in-bounds)
    const int xb  = (int)fminf(fmaxf(ix0, 0.0f), (float)(W_ - 2)); // pair base col
    const int x0c = (int)fminf(fmaxf(ix0, 0.0f), fW1);
    const int x1c = (int)fminf(fmaxf(ix1, 0.0f), fW1);
    const int y0c = (int)fminf(fmaxf(iy0, 0.0f), fH1);
    const int y1c = (int)fminf(fmaxf(iy1, 0.0f), fH1);

    // x-weights with validity folded in (NaN propagates like ref)
    const float wxa = wx0 * vx0;
    const float wxb = wx1 * vx1;
    // Redistribute x-weights onto the fetched pair elements [xb, xb+1].
    const float a0 = (x0c == xb     ? wxa : 0.0f) + (x1c == xb     ? wxb : 0.0f);
    const float a1 = (x0c == xb + 1 ? wxa : 0.0f) + (x1c == xb + 1 ? wxb : 0.0f);
    const float ry0 = wy0 * vy0;
    const float ry1 = wy1 * vy1;

    const int r0 = y0c * W_ + xb;
    const int r1 = y1c * W_ + xb;

    const float* __restrict__ fN = features + (size_t)n * C_ * HW_;
    float* __restrict__ oN = out + (size_t)n * C_ * HW_ + pix;

    // Two-phase software pipeline: issue 16 independent dwordx2 loads
    // (8 channels x 2 rows) before any use. Static indexing -> registers
    // (rule #20). 4 outer iterations cover C=32.
    for (int c0 = 0; c0 < C_; c0 += 8) {
        float2 p0[8], p1[8];
#pragma unroll
        for (int j = 0; j < 8; ++j) {
            const float* __restrict__ fc = fN + (size_t)(c0 + j) * HW_;
            __builtin_memcpy(&p0[j], fc + r0, 8);
            __builtin_memcpy(&p1[j], fc + r1, 8);
        }
#pragma unroll
        for (int j = 0; j < 8; ++j) {
            const float v = (p0[j].x * a0 + p0[j].y * a1) * ry0
                          + (p1[j].x * a0 + p1[j].y * a1) * ry1;
            oN[(size_t)(c0 + j) * HW_] = v;
        }
    }
}

extern "C" void kernel_launch(void* const* d_in, const int* in_sizes, int n_in,
                              void* d_out, int out_size, void* d_ws, size_t ws_size,
                              hipStream_t stream) {
    const float* features    = (const float*)d_in[0];
    const float* projections = (const float*)d_in[1];
    const float* depth       = (const float*)d_in[2];
    float* out = (float*)d_out;

    dim3 block(256, 1, 1);
    dim3 grid(HW_ / 256, B_ * V_, 1);
    feature_projector_kernel<<<grid, block, 0, stream>>>(features, projections, depth, out);
}